// Round 20
// baseline (166.662 us; speedup 1.0000x reference)
//
#include <hip/hip_runtime.h>
#include <hip/hip_bf16.h>

// Pipeline (N=50000, E=1.6M, D=16, NK=2):
//   bhist: bucket (dst>>7) histogram, LDS-private -> global atomic bcount[512]
//   bscan: scan 512 bucket counts (tiny) -> bbase/bcur/off sentinel; packs W
//   partA: bucket-partition edges into 8B records {src|dst<<16, bf16 k pair}
//   partB+conv1: per-128-node-bucket sort -> srcU/kU/off, then (same block,
//                records hot in L2) conv1+mlp1 -> h1 bf16
//   conv2:       wave/node, 8-lane group/edge, bf16 row gather -> h2 bf16
//   mlp2:        MFMA path; h2 bf16 IS the A-fragment
//
// NOTE (round-7): NEVER atomicAdd on __shared__ float in hot loops (678us).
// NOTE (mlp2 R8-R14): vector-ALU mlp2 plateaued 45-56us; MFMA fixed it.
// NOTE (R18): single-block column-sum was 44us at 0.08% occupancy.
// NOTE (R20): launch/latency-bound now (~80MB compulsory HBM ~= 13us);
//   fusing conv1 into partB removes a launch + cold record re-read.

#define EPSV 1e-12f
#define CHUNK 4096      // edges per partA block
#define NB2 512         // bucket slot array size (nbuck = ceil(N/128) = 391)
#define BSH 7           // bucket shift: 128 nodes per bucket
#define BNODES 128      // nodes per bucket
#define BCPAD 16        // bcur padding stride (ints)

typedef unsigned short ushort_t;
typedef unsigned int uint_t;
typedef __attribute__((ext_vector_type(8))) short bf16x8;
typedef __attribute__((ext_vector_type(4))) float f32x4;

// ---- per-block detection of int64 edge_index layout ----
__device__ __forceinline__ int detect_i64_block(const int* ei) {
    __shared__ int nz;
    if (threadIdx.x == 0) nz = 0;
    __syncthreads();
    int v = 0;
    for (int i = threadIdx.x; i < 1024; i += blockDim.x) v |= ei[2 * i + 1];
    if (v) atomicOr(&nz, 1);
    __syncthreads();
    return nz ? 0 : 1;     // 1 => int64 layout
}

__device__ __forceinline__ void load_edge(const int* ei, int e, int E, int flag,
                                          int& src, int& dst) {
    if (flag) {            // int64 storage: low words at even int32 indices
        src = ei[2 * e];
        dst = ei[2 * E + 2 * e];
    } else {               // int32 storage
        src = ei[e];
        dst = ei[E + e];
    }
}

// ---- bf16 helpers ----
__device__ __forceinline__ ushort_t f2bf(float f) {
    uint_t u = __float_as_uint(f);
    uint_t r = u + 0x7FFFu + ((u >> 16) & 1u);
    return (ushort_t)(r >> 16);
}
__device__ __forceinline__ uint_t pack2(float a, float b) {
    return (uint_t)f2bf(a) | ((uint_t)f2bf(b) << 16);
}
__device__ __forceinline__ float unpk_lo(uint_t u) {
    return __uint_as_float(u << 16);
}
__device__ __forceinline__ float unpk_hi(uint_t u) {
    return __uint_as_float(u & 0xFFFF0000u);
}
__device__ __forceinline__ bf16x8 ld_frag(const uint4* p) {
    union { uint4 q; bf16x8 v; } u;
    u.q = *p;
    return u.v;
}

// ---- bucket histogram: LDS-private, flush to global bcount via atomics ----
__global__ __launch_bounds__(256) void bhist_kernel(
        const int* __restrict__ ei, int* __restrict__ bcount, int E) {
    __shared__ int l[NB2];
    int flag = detect_i64_block(ei);
    for (int i = threadIdx.x; i < NB2; i += 256) l[i] = 0;
    __syncthreads();
    int stride = gridDim.x * 256;
    int gid = blockIdx.x * 256 + threadIdx.x;
    if ((E & 3) == 0) {
        if (flag) {
            const int4* p = (const int4*)(ei + 2 * (size_t)E);  // dst pairs
            int total = E >> 1;
            for (int i = gid; i < total; i += stride) {
                int4 v = p[i];
                atomicAdd(&l[v.x >> BSH], 1);
                atomicAdd(&l[v.z >> BSH], 1);
            }
        } else {
            const int4* p = (const int4*)(ei + (size_t)E);
            int total = E >> 2;
            for (int i = gid; i < total; i += stride) {
                int4 v = p[i];
                atomicAdd(&l[v.x >> BSH], 1);
                atomicAdd(&l[v.y >> BSH], 1);
                atomicAdd(&l[v.z >> BSH], 1);
                atomicAdd(&l[v.w >> BSH], 1);
            }
        }
    } else {
        for (int e = gid; e < E; e += stride) {
            int dst = flag ? ei[2 * (size_t)E + 2 * e] : ei[(size_t)E + e];
            atomicAdd(&l[dst >> BSH], 1);
        }
    }
    __syncthreads();
    for (int i = threadIdx.x; i < NB2; i += 256) {
        int c = l[i];
        if (c) atomicAdd(&bcount[i], c);
    }
}

// ---- bscan: scan 512 bucket counts; ALSO packs W2a/W2b B-frags ----
__global__ __launch_bounds__(NB2) void bscan_kernel(
        const int* __restrict__ bcount,
        int* __restrict__ bbase, int* __restrict__ bcur,
        int* __restrict__ off, int nbuck, int E, int N,
        const float* __restrict__ W2a, const float* __restrict__ W2b,
        uint4* __restrict__ wpkA, uint4* __restrict__ wpkB) {
    // packW portion (independent work, 2048 items)
    for (int gid = threadIdx.x; gid < 2048; gid += NB2) {
        if (gid < 1024) {
            int ct = gid >> 7, ks = (gid >> 6) & 1, l = gid & 63;
            int kb = l >> 4, m = l & 15;
            ushort_t us[8];
#pragma unroll
            for (int i = 0; i < 8; i++)
                us[i] = f2bf(W2a[(size_t)(ks * 32 + kb * 8 + i) * 128 + ct * 16 + m]);
            uint4 q;
            q.x = (uint_t)us[0] | ((uint_t)us[1] << 16);
            q.y = (uint_t)us[2] | ((uint_t)us[3] << 16);
            q.z = (uint_t)us[4] | ((uint_t)us[5] << 16);
            q.w = (uint_t)us[6] | ((uint_t)us[7] << 16);
            wpkA[gid] = q;
        } else {
            int e = gid - 1024;
            int ct = e >> 8, ks = (e >> 6) & 3, l = e & 63;
            int kb = l >> 4, m = l & 15;
            ushort_t us[8];
#pragma unroll
            for (int i = 0; i < 8; i++)
                us[i] = f2bf(W2b[(size_t)(ks * 32 + kb * 8 + i) * 64 + ct * 16 + m]);
            uint4 q;
            q.x = (uint_t)us[0] | ((uint_t)us[1] << 16);
            q.y = (uint_t)us[2] | ((uint_t)us[3] << 16);
            q.z = (uint_t)us[4] | ((uint_t)us[5] << 16);
            q.w = (uint_t)us[6] | ((uint_t)us[7] << 16);
            wpkB[e] = q;
        }
    }

    __shared__ int s[NB2];
    int t = threadIdx.x;            // blockDim = NB2
    int c = bcount[t];
    s[t] = c;
    __syncthreads();
    for (int d = 1; d < NB2; d <<= 1) {
        int v = (t >= d) ? s[t - d] : 0;
        __syncthreads();
        s[t] += v;
        __syncthreads();
    }
    int excl = s[t] - c;
    if (t < nbuck) { bbase[t] = excl; bcur[t * BCPAD] = excl; }
    if (t == 0) { bbase[nbuck] = E; off[N] = E; }
}

// ---- partA: bucket-partition; 8B records {sd, kbf}; 512thr, CHUNK=4096 ----
__global__ __launch_bounds__(512) void partA_kernel(
        const float* __restrict__ K, const int* __restrict__ ei,
        int* __restrict__ bcur, uint2* __restrict__ stg8, int E) {
    __shared__ int cnt[NB2];
    __shared__ int bexc[NB2];
    __shared__ int gbase[NB2];
    __shared__ int scanbuf[NB2];
    __shared__ uint2 stage[CHUNK];    // 32 KB

    int flag = detect_i64_block(ei);
    int e0 = blockIdx.x * CHUNK;
    int tot = min(CHUNK, E - e0);
    int t = threadIdx.x;

    cnt[t] = 0;                       // blockDim == NB2 == 512
    __syncthreads();

    int   myslot[CHUNK / 512];
    int   mybk[CHUNK / 512];
    uint2 myrec[CHUNK / 512];
#pragma unroll
    for (int it = 0; it < CHUNK / 512; ++it) {
        int e = e0 + it * 512 + t;
        mybk[it] = -1;
        if (e < E) {
            int src, dst;
            load_edge(ei, e, E, flag, src, dst);
            int bk = dst >> BSH;
            mybk[it] = bk;
            myrec[it].x = (uint_t)src | ((uint_t)dst << 16);
            myrec[it].y = pack2(K[e], K[E + e]);
            myslot[it] = atomicAdd(&cnt[bk], 1);
        }
    }
    __syncthreads();

    // scan NB2 buckets, one per thread
    int c = cnt[t];
    scanbuf[t] = c;
    __syncthreads();
    for (int d = 1; d < NB2; d <<= 1) {
        int v = (t >= d) ? scanbuf[t - d] : 0;
        __syncthreads();
        scanbuf[t] += v;
        __syncthreads();
    }
    int excl = scanbuf[t] - c;
    bexc[t] = excl;
    gbase[t] = c ? atomicAdd(&bcur[t * BCPAD], c) : 0;
    __syncthreads();

#pragma unroll
    for (int it = 0; it < CHUNK / 512; ++it) {
        if (mybk[it] >= 0) stage[bexc[mybk[it]] + myslot[it]] = myrec[it];
    }
    __syncthreads();

    for (int i = t; i < tot; i += 512) {
        uint2 r = stage[i];
        int bk = (int)(r.x >> 16) >> BSH;
        stg8[gbase[bk] + (i - bexc[bk])] = r;
    }
}

// ---- partB + conv1 + mlp1 fused: one block per 128-node bucket ----
// Phase 1: per-node hist/scan -> off, place srcU/kU (bucket-local, L2-hot).
// Phase 2 (same block): conv1 gather + shfl-MLP1 + l2norm -> h1 bf16.
__global__ __launch_bounds__(256) void partB_conv1_kernel(
        const uint2* __restrict__ stg8, const int* __restrict__ bbase,
        int* __restrict__ off, ushort_t* __restrict__ srcU,
        uint_t* __restrict__ kU,
        const float* __restrict__ x, const float* __restrict__ W1,
        const float* __restrict__ b1, ushort_t* __restrict__ h1u, int N) {
    __shared__ int lcnt[BNODES];
    __shared__ int lscan[BNODES];
    __shared__ float w[1024];
    __shared__ float bsh[32];

    int b = blockIdx.x;
    int nodeBase = b << BSH;
    int s0 = bbase[b];
    int s1 = bbase[b + 1];
    int t = threadIdx.x;

    // stage W1/b1 while the histogram pass runs
    for (int i = t; i < 1024; i += 256) w[i] = W1[i];
    if (t < 32) bsh[t] = b1[t];
    if (t < BNODES) lcnt[t] = 0;
    __syncthreads();

    for (int i = s0 + t; i < s1; i += 256)
        atomicAdd(&lcnt[(stg8[i].x >> 16) & (BNODES - 1)], 1);
    __syncthreads();

    if (t < BNODES) lscan[t] = lcnt[t];
    __syncthreads();
    for (int d = 1; d < BNODES; d <<= 1) {
        int v = 0;
        if (t < BNODES && t >= d) v = lscan[t - d];
        __syncthreads();
        if (t < BNODES) lscan[t] += v;
        __syncthreads();
    }
    if (t < BNODES) {
        int node = nodeBase + t;
        if (node < N) {
            int c = lcnt[t];
            int o = s0 + lscan[t] - c;   // exclusive offset, absolute
            off[node] = o;
            lcnt[t] = o;                 // becomes the cursor
        }
    }
    __syncthreads();

    for (int i = s0 + t; i < s1; i += 256) {
        uint2 r = stg8[i];
        int pos = atomicAdd(&lcnt[(r.x >> 16) & (BNODES - 1)], 1);
        srcU[pos] = (ushort_t)(r.x & 0xFFFFu);
        kU[pos] = r.y;
    }
    __threadfence_block();
    __syncthreads();
    // restore cursors -> start offsets for conv1 (lcnt[t] is now end offset)
    // (recompute from lscan: start = s0 + lscan[t] - count; but lcnt was
    //  incremented by count, so start = lcnt[t] - (lscan diff). Simpler:
    //  conv1 reads off[] which this block just wrote (L2-hot).)

    // ---- conv1 + MLP1: half-wave per node, 16 rounds of 8 half-waves ----
    int hw = t >> 5;
    int lane = t & 31;
    int ch = lane & 15;
    int grp = lane >> 4;

    for (int nn = hw; nn < BNODES; nn += 8) {
        int node = nodeBase + nn;
        if (node >= N) break;
        int start = off[node];
        int deg = off[node + 1] - start;   // off[node+1] valid: sentinel at N

        float a0 = 0.f, a1 = 0.f;
        int j = grp;
        for (; j + 6 < deg; j += 8) {
            int p = start + j;
            int q0 = srcU[p], q1 = srcU[p + 2], q2 = srcU[p + 4], q3 = srcU[p + 6];
            uint_t k0 = kU[p], k1 = kU[p + 2], k2 = kU[p + 4], k3 = kU[p + 6];
            float v0 = x[q0 * 16 + ch];
            float v1 = x[q1 * 16 + ch];
            float v2 = x[q2 * 16 + ch];
            float v3 = x[q3 * 16 + ch];
            a0 += unpk_lo(k0) * v0; a1 += unpk_hi(k0) * v0;
            a0 += unpk_lo(k1) * v1; a1 += unpk_hi(k1) * v1;
            a0 += unpk_lo(k2) * v2; a1 += unpk_hi(k2) * v2;
            a0 += unpk_lo(k3) * v3; a1 += unpk_hi(k3) * v3;
        }
        for (; j < deg; j += 2) {
            int p = start + j;
            int s = srcU[p];
            uint_t kk = kU[p];
            float v = x[s * 16 + ch];
            a0 += unpk_lo(kk) * v; a1 += unpk_hi(kk) * v;
        }
        a0 += __shfl_xor(a0, 16, 32);
        a1 += __shfl_xor(a1, 16, 32);
        float acc = grp ? a1 : a0;

        float o = bsh[lane];
#pragma unroll
        for (int q = 0; q < 32; q++) o += __shfl(acc, q, 32) * w[q * 32 + lane];
        o = fmaxf(o, 0.f);
        float ss = o * o;
#pragma unroll
        for (int m = 16; m >= 1; m >>= 1) ss += __shfl_xor(ss, m, 32);
        h1u[node * 32 + lane] = f2bf(o / fmaxf(sqrtf(ss), EPSV));
    }
}

// ---- conv2: wave/node; 8-lane group/edge; bf16 row gather -> h2 bf16 ----
__global__ __launch_bounds__(256) void conv2_gather_kernel(
        const ushort_t* __restrict__ h1u, const ushort_t* __restrict__ srcU,
        const uint_t* __restrict__ kU, const int* __restrict__ off,
        ushort_t* __restrict__ h2u, int N) {
    int wid = threadIdx.x >> 6;
    int lane = threadIdx.x & 63;
    int node = blockIdx.x * 4 + wid;
    if (node >= N) return;

    int grp = lane >> 3;              // 0..7: edge index mod 8
    int cq = lane & 7;                // channel quad: ch = cq*4..cq*4+3
    int start = off[node];
    int deg = off[node + 1] - start;

    float a00 = 0.f, a01 = 0.f, a02 = 0.f, a03 = 0.f;   // k0 * row[cq*4..]
    float a10 = 0.f, a11 = 0.f, a12 = 0.f, a13 = 0.f;   // k1 * row[cq*4..]
    int j = grp;
    for (; j + 8 < deg; j += 16) {    // edges j, j+8
        int p0 = start + j, p1 = p0 + 8;
        int s0 = srcU[p0], s1 = srcU[p1];
        uint_t k0 = kU[p0], k1 = kU[p1];
        uint2 u0 = *(const uint2*)&h1u[s0 * 32 + cq * 4];
        uint2 u1 = *(const uint2*)&h1u[s1 * 32 + cq * 4];
        float k0l = unpk_lo(k0), k0h = unpk_hi(k0);
        float k1l = unpk_lo(k1), k1h = unpk_hi(k1);
        float v00 = unpk_lo(u0.x), v01 = unpk_hi(u0.x);
        float v02 = unpk_lo(u0.y), v03 = unpk_hi(u0.y);
        float v10 = unpk_lo(u1.x), v11 = unpk_hi(u1.x);
        float v12 = unpk_lo(u1.y), v13 = unpk_hi(u1.y);
        a00 += k0l * v00; a01 += k0l * v01; a02 += k0l * v02; a03 += k0l * v03;
        a10 += k0h * v00; a11 += k0h * v01; a12 += k0h * v02; a13 += k0h * v03;
        a00 += k1l * v10; a01 += k1l * v11; a02 += k1l * v12; a03 += k1l * v13;
        a10 += k1h * v10; a11 += k1h * v11; a12 += k1h * v12; a13 += k1h * v13;
    }
    for (; j < deg; j += 8) {
        int p = start + j;
        int s = srcU[p];
        uint_t kk = kU[p];
        uint2 u = *(const uint2*)&h1u[s * 32 + cq * 4];
        float kl = unpk_lo(kk), kh = unpk_hi(kk);
        float v0 = unpk_lo(u.x), v1 = unpk_hi(u.x);
        float v2 = unpk_lo(u.y), v3 = unpk_hi(u.y);
        a00 += kl * v0; a01 += kl * v1; a02 += kl * v2; a03 += kl * v3;
        a10 += kh * v0; a11 += kh * v1; a12 += kh * v2; a13 += kh * v3;
    }

#pragma unroll
    for (int m = 8; m < 64; m <<= 1) {
        a00 += __shfl_xor(a00, m, 64); a01 += __shfl_xor(a01, m, 64);
        a02 += __shfl_xor(a02, m, 64); a03 += __shfl_xor(a03, m, 64);
        a10 += __shfl_xor(a10, m, 64); a11 += __shfl_xor(a11, m, 64);
        a12 += __shfl_xor(a12, m, 64); a13 += __shfl_xor(a13, m, 64);
    }
    if (grp == 0) {
        uint2 o;
        o.x = (uint_t)f2bf(a00) | ((uint_t)f2bf(a01) << 16);
        o.y = (uint_t)f2bf(a02) | ((uint_t)f2bf(a03) << 16);
        *(uint2*)&h2u[(size_t)node * 64 + cq * 4] = o;
    } else if (grp == 1) {
        uint2 o;
        o.x = (uint_t)f2bf(a10) | ((uint_t)f2bf(a11) << 16);
        o.y = (uint_t)f2bf(a12) | ((uint_t)f2bf(a13) << 16);
        *(uint2*)&h2u[(size_t)node * 64 + 32 + cq * 4] = o;
    }
}

// ---- MLP2 via MFMA: 64 nodes/block, 4 waves x 16 nodes each ----
__global__ __launch_bounds__(256) void mlp2_kernel(
        const ushort_t* __restrict__ h2u, const uint4* __restrict__ wpkA,
        const float* __restrict__ b2a, const uint4* __restrict__ wpkB,
        const float* __restrict__ b2b, float* __restrict__ out, int N) {
    __shared__ ushort_t hs[64 * 136];   // 17.4 KB

    int tid = threadIdx.x;
    int w = tid >> 6;          // wave 0..3 -> 16-node M-tile
    int l = tid & 63;
    int m = l & 15;
    int kb = l >> 4;           // 0..3
    int rowbase = w * 16;
    int n0 = blockIdx.x * 64;
    int anode = n0 + rowbase + m;      // A-side node for this lane
    bool alive = anode < N;

    // A-frags for GEMM1 (K=64 -> 2 steps): direct bf16 loads
    bf16x8 a1[2];
#pragma unroll
    for (int ks = 0; ks < 2; ks++) {
        union { uint4 q; bf16x8 v; } u;
        u.q = make_uint4(0, 0, 0, 0);
        if (alive)
            u.q = *(const uint4*)&h2u[(size_t)anode * 64 + ks * 32 + kb * 8];
        a1[ks] = u.v;
    }

    // GEMM1: 8 col-tiles x (2 MFMA) -> H[16][128] bf16 in LDS
#pragma unroll
    for (int ct = 0; ct < 8; ct++) {
        f32x4 acc = {0.f, 0.f, 0.f, 0.f};
        acc = __builtin_amdgcn_mfma_f32_16x16x32_bf16(
                  a1[0], ld_frag(&wpkA[(ct * 2 + 0) * 64 + l]), acc, 0, 0, 0);
        acc = __builtin_amdgcn_mfma_f32_16x16x32_bf16(
                  a1[1], ld_frag(&wpkA[(ct * 2 + 1) * 64 + l]), acc, 0, 0, 0);
        float bias = b2a[ct * 16 + m];
#pragma unroll
        for (int r = 0; r < 4; r++) {
            float hv = fmaxf(acc[r] + bias, 0.f);
            hs[(rowbase + kb * 4 + r) * 136 + ct * 16 + m] = f2bf(hv);
        }
    }
    __syncthreads();

    // A-frags for GEMM2 (K=128 -> 4 steps) from LDS (16B-aligned b128)
    bf16x8 a2[4];
#pragma unroll
    for (int ks = 0; ks < 4; ks++) {
        union { uint4 q; bf16x8 v; } u;
        u.q = *(const uint4*)&hs[(rowbase + m) * 136 + ks * 32 + kb * 8];
        a2[ks] = u.v;
    }

    // GEMM2: 4 col-tiles x (4 MFMA)
    f32x4 acc2[4];
#pragma unroll
    for (int ct = 0; ct < 4; ct++) {
        f32x4 acc = {0.f, 0.f, 0.f, 0.f};
#pragma unroll
        for (int ks = 0; ks < 4; ks++)
            acc = __builtin_amdgcn_mfma_f32_16x16x32_bf16(
                      a2[ks], ld_frag(&wpkB[(ct * 4 + ks) * 64 + l]), acc, 0, 0, 0);
        float bias = b2b[ct * 16 + m];
#pragma unroll
        for (int r = 0; r < 4; r++) acc2[ct][r] = acc[r] + bias;
    }

    // l2norm: lane holds rows kb*4+r, cols {ct*16+m}
#pragma unroll
    for (int r = 0; r < 4; r++) {
        float ss = acc2[0][r] * acc2[0][r] + acc2[1][r] * acc2[1][r] +
                   acc2[2][r] * acc2[2][r] + acc2[3][r] * acc2[3][r];
        ss += __shfl_xor(ss, 1, 16);
        ss += __shfl_xor(ss, 2, 16);
        ss += __shfl_xor(ss, 4, 16);
        ss += __shfl_xor(ss, 8, 16);
        float invn = 1.0f / fmaxf(sqrtf(ss), EPSV);
        int nrow = n0 + rowbase + kb * 4 + r;
        if (nrow < N) {
#pragma unroll
            for (int ct = 0; ct < 4; ct++)
                out[(size_t)nrow * 64 + ct * 16 + m] = acc2[ct][r] * invn;
        }
    }
}

extern "C" void kernel_launch(void* const* d_in, const int* in_sizes, int n_in,
                              void* d_out, int out_size, void* d_ws, size_t ws_size,
                              hipStream_t stream) {
    const float* x   = (const float*)d_in[0];
    const float* K   = (const float*)d_in[1];
    const int*   ei  = (const int*)d_in[2];
    const float* W1  = (const float*)d_in[3];
    const float* b1  = (const float*)d_in[4];
    const float* W2a = (const float*)d_in[5];
    const float* b2a = (const float*)d_in[6];
    const float* W2b = (const float*)d_in[7];
    const float* b2b = (const float*)d_in[8];
    float* out = (float*)d_out;

    const int D  = 16;
    const int NK = 2;
    const int N  = in_sizes[0] / D;        // 50000 (src,dst < 2^16)
    const int E  = in_sizes[1] / NK;       // 1600000
    const int nbuck = (N + BNODES - 1) >> BSH;  // 391 <= NB2
    const int HROWS = 256;                 // bhist blocks

    // workspace layout:
    //   region0 (overlaid in time):
    //     phase 1 (CSR build): stg8 uint2[E]                    (E*8 B)
    //     phase 2+3:           h2u bf16[N*64] | h1u bf16[N*32]  (N*192 B)
    //   then: kU uint[E] | srcU ushort[E] | off[N+1] | bcount[NB2] |
    //         bbase[NB2+1] | bcur[NB2*BCPAD] | wpkA[1024] | wpkB[1024] uint4
    size_t region0 = (size_t)E * 8;
    size_t hbytes  = (size_t)N * 192;
    if (hbytes > region0) region0 = hbytes;

    ushort_t* h2u   = (ushort_t*)d_ws;
    ushort_t* h1u   = h2u + (size_t)N * 64;
    uint2* stg8     = (uint2*)d_ws;                   // phase 1
    uint_t* kU      = (uint_t*)((char*)d_ws + region0);
    ushort_t* srcU  = (ushort_t*)(kU + (size_t)E);
    int* off        = (int*)(((size_t)(srcU + (size_t)E) + 3) & ~(size_t)3);
    int* bcount     = off + (N + 1);
    int* bbase      = bcount + NB2;
    int* bcur       = bbase + NB2 + 1;
    char* wp        = (char*)(bcur + NB2 * BCPAD);
    wp = (char*)(((size_t)wp + 15) & ~(size_t)15);
    uint4* wpkA     = (uint4*)wp;
    uint4* wpkB     = wpkA + 1024;

    hipMemsetAsync(bcount, 0, NB2 * sizeof(int), stream);
    bhist_kernel<<<HROWS, 256, 0, stream>>>(ei, bcount, E);
    bscan_kernel<<<1, NB2, 0, stream>>>(bcount, bbase, bcur, off,
                                        nbuck, E, N, W2a, W2b, wpkA, wpkB);

    int ablocks = (E + CHUNK - 1) / CHUNK;
    partA_kernel<<<ablocks, 512, 0, stream>>>(K, ei, bcur, stg8, E);
    partB_conv1_kernel<<<nbuck, 256, 0, stream>>>(stg8, bbase, off, srcU, kU,
                                                  x, W1, b1, h1u, N);

    conv2_gather_kernel<<<(N + 3) / 4, 256, 0, stream>>>(h1u, srcU, kU, off,
                                                         h2u, N);
    mlp2_kernel<<<(N + 63) / 64, 256, 0, stream>>>(h2u, wpkA, b2a, wpkB, b2b,
                                                   out, N);
}

// Round 21
// 136.084 us; speedup vs baseline: 1.2247x; 1.2247x over previous
//
#include <hip/hip_runtime.h>
#include <hip/hip_bf16.h>

// Pipeline (N=50000, E=1.6M, D=16, NK=2):
//   bhist: bucket (dst>>7) histogram, LDS-private -> global atomic bcount[512]
//   bscan: scan 512 bucket counts (tiny) -> bbase/bcur/off sentinel; packs W
//   partA: bucket-partition edges into 8B records {src|dst<<16, bf16 k pair}
//   partB: per-128-node-bucket sort -> srcU(u16) + kU(bf16 pair) + off
//   conv1+mlp1: half-wave/node, 16-lane group/edge -> h1 bf16 (L2-fits)
//   conv2:      wave/node, 8-lane group/edge, bf16 row gather -> h2 bf16
//   mlp2:       MFMA path; h2 bf16 IS the A-fragment
//
// NOTE (round-7): NEVER atomicAdd on __shared__ float in hot loops (678us).
// NOTE (mlp2 R8-R14): vector-ALU mlp2 plateaued 45-56us; MFMA fixed it.
// NOTE (R18): single-block column-sum was 44us at 0.08% occupancy.
// NOTE (R20): fusing conv1 into partB COLLAPSED occupancy (391-block grid
//   for a phase that needs 6250 blocks): 33us -> 86us. Fusion only pays
//   when grid widths match. This is the R19 structure (best: 135us).

#define EPSV 1e-12f
#define CHUNK 4096      // edges per partA block
#define NB2 512         // bucket slot array size (nbuck = ceil(N/128) = 391)
#define BSH 7           // bucket shift: 128 nodes per bucket
#define BNODES 128      // nodes per bucket
#define BCPAD 16        // bcur padding stride (ints)

typedef unsigned short ushort_t;
typedef unsigned int uint_t;
typedef __attribute__((ext_vector_type(8))) short bf16x8;
typedef __attribute__((ext_vector_type(4))) float f32x4;

// ---- per-block detection of int64 edge_index layout ----
__device__ __forceinline__ int detect_i64_block(const int* ei) {
    __shared__ int nz;
    if (threadIdx.x == 0) nz = 0;
    __syncthreads();
    int v = 0;
    for (int i = threadIdx.x; i < 1024; i += blockDim.x) v |= ei[2 * i + 1];
    if (v) atomicOr(&nz, 1);
    __syncthreads();
    return nz ? 0 : 1;     // 1 => int64 layout
}

__device__ __forceinline__ void load_edge(const int* ei, int e, int E, int flag,
                                          int& src, int& dst) {
    if (flag) {            // int64 storage: low words at even int32 indices
        src = ei[2 * e];
        dst = ei[2 * E + 2 * e];
    } else {               // int32 storage
        src = ei[e];
        dst = ei[E + e];
    }
}

// ---- bf16 helpers ----
__device__ __forceinline__ ushort_t f2bf(float f) {
    uint_t u = __float_as_uint(f);
    uint_t r = u + 0x7FFFu + ((u >> 16) & 1u);
    return (ushort_t)(r >> 16);
}
__device__ __forceinline__ uint_t pack2(float a, float b) {
    return (uint_t)f2bf(a) | ((uint_t)f2bf(b) << 16);
}
__device__ __forceinline__ float unpk_lo(uint_t u) {
    return __uint_as_float(u << 16);
}
__device__ __forceinline__ float unpk_hi(uint_t u) {
    return __uint_as_float(u & 0xFFFF0000u);
}
__device__ __forceinline__ bf16x8 ld_frag(const uint4* p) {
    union { uint4 q; bf16x8 v; } u;
    u.q = *p;
    return u.v;
}

// ---- bucket histogram: LDS-private, flush to global bcount via atomics ----
__global__ __launch_bounds__(256) void bhist_kernel(
        const int* __restrict__ ei, int* __restrict__ bcount, int E) {
    __shared__ int l[NB2];
    int flag = detect_i64_block(ei);
    for (int i = threadIdx.x; i < NB2; i += 256) l[i] = 0;
    __syncthreads();
    int stride = gridDim.x * 256;
    int gid = blockIdx.x * 256 + threadIdx.x;
    if ((E & 3) == 0) {
        if (flag) {
            const int4* p = (const int4*)(ei + 2 * (size_t)E);  // dst pairs
            int total = E >> 1;
            for (int i = gid; i < total; i += stride) {
                int4 v = p[i];
                atomicAdd(&l[v.x >> BSH], 1);
                atomicAdd(&l[v.z >> BSH], 1);
            }
        } else {
            const int4* p = (const int4*)(ei + (size_t)E);
            int total = E >> 2;
            for (int i = gid; i < total; i += stride) {
                int4 v = p[i];
                atomicAdd(&l[v.x >> BSH], 1);
                atomicAdd(&l[v.y >> BSH], 1);
                atomicAdd(&l[v.z >> BSH], 1);
                atomicAdd(&l[v.w >> BSH], 1);
            }
        }
    } else {
        for (int e = gid; e < E; e += stride) {
            int dst = flag ? ei[2 * (size_t)E + 2 * e] : ei[(size_t)E + e];
            atomicAdd(&l[dst >> BSH], 1);
        }
    }
    __syncthreads();
    for (int i = threadIdx.x; i < NB2; i += 256) {
        int c = l[i];
        if (c) atomicAdd(&bcount[i], c);
    }
}

// ---- bscan: scan 512 bucket counts; ALSO packs W2a/W2b B-frags ----
__global__ __launch_bounds__(NB2) void bscan_kernel(
        const int* __restrict__ bcount,
        int* __restrict__ bbase, int* __restrict__ bcur,
        int* __restrict__ off, int nbuck, int E, int N,
        const float* __restrict__ W2a, const float* __restrict__ W2b,
        uint4* __restrict__ wpkA, uint4* __restrict__ wpkB) {
    // packW portion (independent work, 2048 items)
    for (int gid = threadIdx.x; gid < 2048; gid += NB2) {
        if (gid < 1024) {
            int ct = gid >> 7, ks = (gid >> 6) & 1, l = gid & 63;
            int kb = l >> 4, m = l & 15;
            ushort_t us[8];
#pragma unroll
            for (int i = 0; i < 8; i++)
                us[i] = f2bf(W2a[(size_t)(ks * 32 + kb * 8 + i) * 128 + ct * 16 + m]);
            uint4 q;
            q.x = (uint_t)us[0] | ((uint_t)us[1] << 16);
            q.y = (uint_t)us[2] | ((uint_t)us[3] << 16);
            q.z = (uint_t)us[4] | ((uint_t)us[5] << 16);
            q.w = (uint_t)us[6] | ((uint_t)us[7] << 16);
            wpkA[gid] = q;
        } else {
            int e = gid - 1024;
            int ct = e >> 8, ks = (e >> 6) & 3, l = e & 63;
            int kb = l >> 4, m = l & 15;
            ushort_t us[8];
#pragma unroll
            for (int i = 0; i < 8; i++)
                us[i] = f2bf(W2b[(size_t)(ks * 32 + kb * 8 + i) * 64 + ct * 16 + m]);
            uint4 q;
            q.x = (uint_t)us[0] | ((uint_t)us[1] << 16);
            q.y = (uint_t)us[2] | ((uint_t)us[3] << 16);
            q.z = (uint_t)us[4] | ((uint_t)us[5] << 16);
            q.w = (uint_t)us[6] | ((uint_t)us[7] << 16);
            wpkB[e] = q;
        }
    }

    __shared__ int s[NB2];
    int t = threadIdx.x;            // blockDim = NB2
    int c = bcount[t];
    s[t] = c;
    __syncthreads();
    for (int d = 1; d < NB2; d <<= 1) {
        int v = (t >= d) ? s[t - d] : 0;
        __syncthreads();
        s[t] += v;
        __syncthreads();
    }
    int excl = s[t] - c;
    if (t < nbuck) { bbase[t] = excl; bcur[t * BCPAD] = excl; }
    if (t == 0) { bbase[nbuck] = E; off[N] = E; }
}

// ---- partA: bucket-partition; 8B records {sd, kbf}; 512thr, CHUNK=4096 ----
__global__ __launch_bounds__(512) void partA_kernel(
        const float* __restrict__ K, const int* __restrict__ ei,
        int* __restrict__ bcur, uint2* __restrict__ stg8, int E) {
    __shared__ int cnt[NB2];
    __shared__ int bexc[NB2];
    __shared__ int gbase[NB2];
    __shared__ int scanbuf[NB2];
    __shared__ uint2 stage[CHUNK];    // 32 KB

    int flag = detect_i64_block(ei);
    int e0 = blockIdx.x * CHUNK;
    int tot = min(CHUNK, E - e0);
    int t = threadIdx.x;

    cnt[t] = 0;                       // blockDim == NB2 == 512
    __syncthreads();

    int   myslot[CHUNK / 512];
    int   mybk[CHUNK / 512];
    uint2 myrec[CHUNK / 512];
#pragma unroll
    for (int it = 0; it < CHUNK / 512; ++it) {
        int e = e0 + it * 512 + t;
        mybk[it] = -1;
        if (e < E) {
            int src, dst;
            load_edge(ei, e, E, flag, src, dst);
            int bk = dst >> BSH;
            mybk[it] = bk;
            myrec[it].x = (uint_t)src | ((uint_t)dst << 16);
            myrec[it].y = pack2(K[e], K[E + e]);
            myslot[it] = atomicAdd(&cnt[bk], 1);
        }
    }
    __syncthreads();

    // scan NB2 buckets, one per thread
    int c = cnt[t];
    scanbuf[t] = c;
    __syncthreads();
    for (int d = 1; d < NB2; d <<= 1) {
        int v = (t >= d) ? scanbuf[t - d] : 0;
        __syncthreads();
        scanbuf[t] += v;
        __syncthreads();
    }
    int excl = scanbuf[t] - c;
    bexc[t] = excl;
    gbase[t] = c ? atomicAdd(&bcur[t * BCPAD], c) : 0;
    __syncthreads();

#pragma unroll
    for (int it = 0; it < CHUNK / 512; ++it) {
        if (mybk[it] >= 0) stage[bexc[mybk[it]] + myslot[it]] = myrec[it];
    }
    __syncthreads();

    for (int i = t; i < tot; i += 512) {
        uint2 r = stage[i];
        int bk = (int)(r.x >> 16) >> BSH;
        stg8[gbase[bk] + (i - bexc[bk])] = r;
    }
}

// ---- partB: one block per 128-node bucket; hist pass reads 8B/edge ----
__global__ __launch_bounds__(256) void partB_kernel(
        const uint2* __restrict__ stg8, const int* __restrict__ bbase,
        int* __restrict__ off, ushort_t* __restrict__ srcU,
        uint_t* __restrict__ kU, int N) {
    __shared__ int lcnt[BNODES];
    __shared__ int lscan[BNODES];

    int b = blockIdx.x;
    int nodeBase = b << BSH;
    int s0 = bbase[b];
    int s1 = bbase[b + 1];
    int t = threadIdx.x;

    if (t < BNODES) lcnt[t] = 0;
    __syncthreads();

    for (int i = s0 + t; i < s1; i += 256)
        atomicAdd(&lcnt[(stg8[i].x >> 16) & (BNODES - 1)], 1);
    __syncthreads();

    if (t < BNODES) lscan[t] = lcnt[t];
    __syncthreads();
    for (int d = 1; d < BNODES; d <<= 1) {
        int v = 0;
        if (t < BNODES && t >= d) v = lscan[t - d];
        __syncthreads();
        if (t < BNODES) lscan[t] += v;
        __syncthreads();
    }
    if (t < BNODES) {
        int node = nodeBase + t;
        if (node < N) {
            int c = lcnt[t];
            int o = s0 + lscan[t] - c;   // exclusive offset, absolute
            off[node] = o;
            lcnt[t] = o;                 // becomes the cursor
        }
    }
    __syncthreads();

    for (int i = s0 + t; i < s1; i += 256) {
        uint2 r = stg8[i];
        int pos = atomicAdd(&lcnt[(r.x >> 16) & (BNODES - 1)], 1);
        srcU[pos] = (ushort_t)(r.x & 0xFFFFu);
        kU[pos] = r.y;
    }
}

// ---- conv1 + MLP1: half-wave per node; 16-lane group per edge -> h1 bf16 ----
__global__ __launch_bounds__(256) void conv1_mlp1_kernel(
        const float* __restrict__ x, const ushort_t* __restrict__ srcU,
        const uint_t* __restrict__ kU, const int* __restrict__ off,
        const float* __restrict__ W1, const float* __restrict__ b1,
        ushort_t* __restrict__ h1u, int N) {
    __shared__ float w[1024];
    __shared__ float bsh[32];
    for (int i = threadIdx.x; i < 1024; i += 256) w[i] = W1[i];
    if (threadIdx.x < 32) bsh[threadIdx.x] = b1[threadIdx.x];
    __syncthreads();

    int hw = threadIdx.x >> 5;        // half-wave 0..7 -> node
    int lane = threadIdx.x & 31;
    int node = blockIdx.x * 8 + hw;
    if (node >= N) return;

    int ch = lane & 15;
    int grp = lane >> 4;              // 0/1: edge parity
    int start = off[node];
    int deg = off[node + 1] - start;

    float a0 = 0.f, a1 = 0.f;
    int j = grp;
    for (; j + 6 < deg; j += 8) {     // edges j, j+2, j+4, j+6
        int p = start + j;
        int s0 = srcU[p], s1 = srcU[p + 2], s2 = srcU[p + 4], s3 = srcU[p + 6];
        uint_t k0 = kU[p], k1 = kU[p + 2], k2 = kU[p + 4], k3 = kU[p + 6];
        float v0 = x[s0 * 16 + ch];
        float v1 = x[s1 * 16 + ch];
        float v2 = x[s2 * 16 + ch];
        float v3 = x[s3 * 16 + ch];
        a0 += unpk_lo(k0) * v0; a1 += unpk_hi(k0) * v0;
        a0 += unpk_lo(k1) * v1; a1 += unpk_hi(k1) * v1;
        a0 += unpk_lo(k2) * v2; a1 += unpk_hi(k2) * v2;
        a0 += unpk_lo(k3) * v3; a1 += unpk_hi(k3) * v3;
    }
    for (; j < deg; j += 2) {
        int p = start + j;
        int s = srcU[p];
        uint_t kk = kU[p];
        float v = x[s * 16 + ch];
        a0 += unpk_lo(kk) * v; a1 += unpk_hi(kk) * v;
    }
    a0 += __shfl_xor(a0, 16, 32);
    a1 += __shfl_xor(a1, 16, 32);
    float acc = grp ? a1 : a0;

    float o = bsh[lane];
#pragma unroll
    for (int q = 0; q < 32; q++) o += __shfl(acc, q, 32) * w[q * 32 + lane];
    o = fmaxf(o, 0.f);
    float ss = o * o;
#pragma unroll
    for (int m = 16; m >= 1; m >>= 1) ss += __shfl_xor(ss, m, 32);
    h1u[node * 32 + lane] = f2bf(o / fmaxf(sqrtf(ss), EPSV));
}

// ---- conv2: wave/node; 8-lane group/edge; bf16 row gather -> h2 bf16 ----
__global__ __launch_bounds__(256) void conv2_gather_kernel(
        const ushort_t* __restrict__ h1u, const ushort_t* __restrict__ srcU,
        const uint_t* __restrict__ kU, const int* __restrict__ off,
        ushort_t* __restrict__ h2u, int N) {
    int wid = threadIdx.x >> 6;
    int lane = threadIdx.x & 63;
    int node = blockIdx.x * 4 + wid;
    if (node >= N) return;

    int grp = lane >> 3;              // 0..7: edge index mod 8
    int cq = lane & 7;                // channel quad: ch = cq*4..cq*4+3
    int start = off[node];
    int deg = off[node + 1] - start;

    float a00 = 0.f, a01 = 0.f, a02 = 0.f, a03 = 0.f;   // k0 * row[cq*4..]
    float a10 = 0.f, a11 = 0.f, a12 = 0.f, a13 = 0.f;   // k1 * row[cq*4..]
    int j = grp;
    for (; j + 8 < deg; j += 16) {    // edges j, j+8
        int p0 = start + j, p1 = p0 + 8;
        int s0 = srcU[p0], s1 = srcU[p1];
        uint_t k0 = kU[p0], k1 = kU[p1];
        uint2 u0 = *(const uint2*)&h1u[s0 * 32 + cq * 4];
        uint2 u1 = *(const uint2*)&h1u[s1 * 32 + cq * 4];
        float k0l = unpk_lo(k0), k0h = unpk_hi(k0);
        float k1l = unpk_lo(k1), k1h = unpk_hi(k1);
        float v00 = unpk_lo(u0.x), v01 = unpk_hi(u0.x);
        float v02 = unpk_lo(u0.y), v03 = unpk_hi(u0.y);
        float v10 = unpk_lo(u1.x), v11 = unpk_hi(u1.x);
        float v12 = unpk_lo(u1.y), v13 = unpk_hi(u1.y);
        a00 += k0l * v00; a01 += k0l * v01; a02 += k0l * v02; a03 += k0l * v03;
        a10 += k0h * v00; a11 += k0h * v01; a12 += k0h * v02; a13 += k0h * v03;
        a00 += k1l * v10; a01 += k1l * v11; a02 += k1l * v12; a03 += k1l * v13;
        a10 += k1h * v10; a11 += k1h * v11; a12 += k1h * v12; a13 += k1h * v13;
    }
    for (; j < deg; j += 8) {
        int p = start + j;
        int s = srcU[p];
        uint_t kk = kU[p];
        uint2 u = *(const uint2*)&h1u[s * 32 + cq * 4];
        float kl = unpk_lo(kk), kh = unpk_hi(kk);
        float v0 = unpk_lo(u.x), v1 = unpk_hi(u.x);
        float v2 = unpk_lo(u.y), v3 = unpk_hi(u.y);
        a00 += kl * v0; a01 += kl * v1; a02 += kl * v2; a03 += kl * v3;
        a10 += kh * v0; a11 += kh * v1; a12 += kh * v2; a13 += kh * v3;
    }

#pragma unroll
    for (int m = 8; m < 64; m <<= 1) {
        a00 += __shfl_xor(a00, m, 64); a01 += __shfl_xor(a01, m, 64);
        a02 += __shfl_xor(a02, m, 64); a03 += __shfl_xor(a03, m, 64);
        a10 += __shfl_xor(a10, m, 64); a11 += __shfl_xor(a11, m, 64);
        a12 += __shfl_xor(a12, m, 64); a13 += __shfl_xor(a13, m, 64);
    }
    if (grp == 0) {
        uint2 o;
        o.x = (uint_t)f2bf(a00) | ((uint_t)f2bf(a01) << 16);
        o.y = (uint_t)f2bf(a02) | ((uint_t)f2bf(a03) << 16);
        *(uint2*)&h2u[(size_t)node * 64 + cq * 4] = o;
    } else if (grp == 1) {
        uint2 o;
        o.x = (uint_t)f2bf(a10) | ((uint_t)f2bf(a11) << 16);
        o.y = (uint_t)f2bf(a12) | ((uint_t)f2bf(a13) << 16);
        *(uint2*)&h2u[(size_t)node * 64 + 32 + cq * 4] = o;
    }
}

// ---- MLP2 via MFMA: 64 nodes/block, 4 waves x 16 nodes each ----
__global__ __launch_bounds__(256) void mlp2_kernel(
        const ushort_t* __restrict__ h2u, const uint4* __restrict__ wpkA,
        const float* __restrict__ b2a, const uint4* __restrict__ wpkB,
        const float* __restrict__ b2b, float* __restrict__ out, int N) {
    __shared__ ushort_t hs[64 * 136];   // 17.4 KB

    int tid = threadIdx.x;
    int w = tid >> 6;          // wave 0..3 -> 16-node M-tile
    int l = tid & 63;
    int m = l & 15;
    int kb = l >> 4;           // 0..3
    int rowbase = w * 16;
    int n0 = blockIdx.x * 64;
    int anode = n0 + rowbase + m;      // A-side node for this lane
    bool alive = anode < N;

    // A-frags for GEMM1 (K=64 -> 2 steps): direct bf16 loads
    bf16x8 a1[2];
#pragma unroll
    for (int ks = 0; ks < 2; ks++) {
        union { uint4 q; bf16x8 v; } u;
        u.q = make_uint4(0, 0, 0, 0);
        if (alive)
            u.q = *(const uint4*)&h2u[(size_t)anode * 64 + ks * 32 + kb * 8];
        a1[ks] = u.v;
    }

    // GEMM1: 8 col-tiles x (2 MFMA) -> H[16][128] bf16 in LDS
#pragma unroll
    for (int ct = 0; ct < 8; ct++) {
        f32x4 acc = {0.f, 0.f, 0.f, 0.f};
        acc = __builtin_amdgcn_mfma_f32_16x16x32_bf16(
                  a1[0], ld_frag(&wpkA[(ct * 2 + 0) * 64 + l]), acc, 0, 0, 0);
        acc = __builtin_amdgcn_mfma_f32_16x16x32_bf16(
                  a1[1], ld_frag(&wpkA[(ct * 2 + 1) * 64 + l]), acc, 0, 0, 0);
        float bias = b2a[ct * 16 + m];
#pragma unroll
        for (int r = 0; r < 4; r++) {
            float hv = fmaxf(acc[r] + bias, 0.f);
            hs[(rowbase + kb * 4 + r) * 136 + ct * 16 + m] = f2bf(hv);
        }
    }
    __syncthreads();

    // A-frags for GEMM2 (K=128 -> 4 steps) from LDS (16B-aligned b128)
    bf16x8 a2[4];
#pragma unroll
    for (int ks = 0; ks < 4; ks++) {
        union { uint4 q; bf16x8 v; } u;
        u.q = *(const uint4*)&hs[(rowbase + m) * 136 + ks * 32 + kb * 8];
        a2[ks] = u.v;
    }

    // GEMM2: 4 col-tiles x (4 MFMA)
    f32x4 acc2[4];
#pragma unroll
    for (int ct = 0; ct < 4; ct++) {
        f32x4 acc = {0.f, 0.f, 0.f, 0.f};
#pragma unroll
        for (int ks = 0; ks < 4; ks++)
            acc = __builtin_amdgcn_mfma_f32_16x16x32_bf16(
                      a2[ks], ld_frag(&wpkB[(ct * 4 + ks) * 64 + l]), acc, 0, 0, 0);
        float bias = b2b[ct * 16 + m];
#pragma unroll
        for (int r = 0; r < 4; r++) acc2[ct][r] = acc[r] + bias;
    }

    // l2norm: lane holds rows kb*4+r, cols {ct*16+m}
#pragma unroll
    for (int r = 0; r < 4; r++) {
        float ss = acc2[0][r] * acc2[0][r] + acc2[1][r] * acc2[1][r] +
                   acc2[2][r] * acc2[2][r] + acc2[3][r] * acc2[3][r];
        ss += __shfl_xor(ss, 1, 16);
        ss += __shfl_xor(ss, 2, 16);
        ss += __shfl_xor(ss, 4, 16);
        ss += __shfl_xor(ss, 8, 16);
        float invn = 1.0f / fmaxf(sqrtf(ss), EPSV);
        int nrow = n0 + rowbase + kb * 4 + r;
        if (nrow < N) {
#pragma unroll
            for (int ct = 0; ct < 4; ct++)
                out[(size_t)nrow * 64 + ct * 16 + m] = acc2[ct][r] * invn;
        }
    }
}

extern "C" void kernel_launch(void* const* d_in, const int* in_sizes, int n_in,
                              void* d_out, int out_size, void* d_ws, size_t ws_size,
                              hipStream_t stream) {
    const float* x   = (const float*)d_in[0];
    const float* K   = (const float*)d_in[1];
    const int*   ei  = (const int*)d_in[2];
    const float* W1  = (const float*)d_in[3];
    const float* b1  = (const float*)d_in[4];
    const float* W2a = (const float*)d_in[5];
    const float* b2a = (const float*)d_in[6];
    const float* W2b = (const float*)d_in[7];
    const float* b2b = (const float*)d_in[8];
    float* out = (float*)d_out;

    const int D  = 16;
    const int NK = 2;
    const int N  = in_sizes[0] / D;        // 50000 (src,dst < 2^16)
    const int E  = in_sizes[1] / NK;       // 1600000
    const int nbuck = (N + BNODES - 1) >> BSH;  // 391 <= NB2
    const int HROWS = 256;                 // bhist blocks

    // workspace layout:
    //   region0 (overlaid in time):
    //     phase 1 (CSR build): stg8 uint2[E]                    (E*8 B)
    //     phase 2+3:           h2u bf16[N*64] | h1u bf16[N*32]  (N*192 B)
    //   then: kU uint[E] | srcU ushort[E] | off[N+1] | bcount[NB2] |
    //         bbase[NB2+1] | bcur[NB2*BCPAD] | wpkA[1024] | wpkB[1024] uint4
    size_t region0 = (size_t)E * 8;
    size_t hbytes  = (size_t)N * 192;
    if (hbytes > region0) region0 = hbytes;

    ushort_t* h2u   = (ushort_t*)d_ws;
    ushort_t* h1u   = h2u + (size_t)N * 64;
    uint2* stg8     = (uint2*)d_ws;                   // phase 1
    uint_t* kU      = (uint_t*)((char*)d_ws + region0);
    ushort_t* srcU  = (ushort_t*)(kU + (size_t)E);
    int* off        = (int*)(((size_t)(srcU + (size_t)E) + 3) & ~(size_t)3);
    int* bcount     = off + (N + 1);
    int* bbase      = bcount + NB2;
    int* bcur       = bbase + NB2 + 1;
    char* wp        = (char*)(bcur + NB2 * BCPAD);
    wp = (char*)(((size_t)wp + 15) & ~(size_t)15);
    uint4* wpkA     = (uint4*)wp;
    uint4* wpkB     = wpkA + 1024;

    hipMemsetAsync(bcount, 0, NB2 * sizeof(int), stream);
    bhist_kernel<<<HROWS, 256, 0, stream>>>(ei, bcount, E);
    bscan_kernel<<<1, NB2, 0, stream>>>(bcount, bbase, bcur, off,
                                        nbuck, E, N, W2a, W2b, wpkA, wpkB);

    int ablocks = (E + CHUNK - 1) / CHUNK;
    partA_kernel<<<ablocks, 512, 0, stream>>>(K, ei, bcur, stg8, E);
    partB_kernel<<<nbuck, 256, 0, stream>>>(stg8, bbase, off, srcU, kU, N);

    conv1_mlp1_kernel<<<(N + 7) / 8, 256, 0, stream>>>(x, srcU, kU, off,
                                                       W1, b1, h1u, N);
    conv2_gather_kernel<<<(N + 3) / 4, 256, 0, stream>>>(h1u, srcU, kU, off,
                                                         h2u, N);
    mlp2_kernel<<<(N + 63) / 64, 256, 0, stream>>>(h2u, wpkA, b2a, wpkB, b2b,
                                                   out, N);
}